// Round 4
// baseline (405.903 us; speedup 1.0000x reference)
//
#include <hip/hip_runtime.h>
#include <math.h>

#define BB 8
#define TT 100
#define HH 1024
#define LL 512
#define VV 32000
#define NROWS (BB*TT)   // 800
#define MPAD 896        // 7 tiles of 128
#define NMT 7           // m tiles
#define NNT 250         // n tiles
#define NWG (NMT*NNT)   // 1750

typedef __bf16 bf16x8 __attribute__((ext_vector_type(8)));
typedef __bf16 bf16x4 __attribute__((ext_vector_type(4)));
typedef float f32x4 __attribute__((ext_vector_type(4)));

__device__ __forceinline__ void gload16(const void* g, void* l) {
  __builtin_amdgcn_global_load_lds(
      (const __attribute__((address_space(1))) unsigned int*)g,
      (__attribute__((address_space(3))) unsigned int*)l, 16, 0, 0);
}

// ---------- kernel 1: x fp32 -> bf16, zero-padded to 896 rows ----------
__global__ __launch_bounds__(256) void k_cvt_x(const float* __restrict__ x,
                                               __bf16* __restrict__ xb) {
  int idx = blockIdx.x * 256 + threadIdx.x;   // one float4 per thread
  int row = (idx * 4) >> 10;
  bf16x4 v;
  if (row < NROWS) {
    float4 f = ((const float4*)x)[idx];
    v[0] = (__bf16)f.x; v[1] = (__bf16)f.y; v[2] = (__bf16)f.z; v[3] = (__bf16)f.w;
  } else {
    v[0] = v[1] = v[2] = v[3] = (__bf16)0.f;
  }
  ((bf16x4*)xb)[idx] = v;
}

// ---------- kernel 2: W [1024][32000] fp32 -> blocked Wt [kt][n][32] bf16 ----
__global__ __launch_bounds__(256) void k_cvt_wT(const float* __restrict__ W,
                                                __bf16* __restrict__ Wtb) {
  __shared__ float T[32][257];
  int n0 = blockIdx.x * 256;   // 125 blocks
  int kt = blockIdx.y;         // 32 blocks
  int tid = threadIdx.x;
#pragma unroll
  for (int i = 0; i < 32; ++i)
    T[i][tid] = W[(size_t)(kt * 32 + i) * VV + n0 + tid];
  __syncthreads();
  int cq = tid & 3;    // k-chunk (8 k each)
  int cl = tid >> 2;   // 0..63
  __bf16* base = Wtb + ((size_t)kt * VV + n0) * 32;
#pragma unroll
  for (int g = 0; g < 4; ++g) {
    int col = g * 64 + cl;
    bf16x8 v;
#pragma unroll
    for (int j = 0; j < 8; ++j) v[j] = (__bf16)T[cq * 8 + j][col];
    *(bf16x8*)(base + (size_t)col * 32 + cq * 8) = v;
  }
}

// ---------- kernel 3: p_gen + copy distribution (+ rsum zero-init) ----------
__global__ __launch_bounds__(256) void k_pgen_copy(
    const float* __restrict__ x, const float* __restrict__ attn,
    const float* __restrict__ w_gen, const float* __restrict__ b_gen,
    float* __restrict__ p_gen, float* __restrict__ copy_dist,
    float* __restrict__ rsum) {
  int r = blockIdx.x;
  int tid = threadIdx.x;
  __shared__ float red[4];
  if (tid == 0) rsum[r] = 0.f;

  float d = 0.f;
  for (int h = tid; h < HH; h += 256) d += x[(size_t)r * HH + h] * w_gen[h];
#pragma unroll
  for (int o = 32; o > 0; o >>= 1) d += __shfl_down(d, o, 64);
  if ((tid & 63) == 0) red[tid >> 6] = d;
  __syncthreads();
  float dot = red[0] + red[1] + red[2] + red[3];
  float p = 1.f / (1.f + __expf(-(dot + b_gen[0])));
  if (tid == 0) p_gen[r] = p;

  float a0 = attn[(size_t)r * LL + tid];
  float a1 = attn[(size_t)r * LL + 256 + tid];
  float m = fmaxf(a0, a1);
#pragma unroll
  for (int o = 32; o > 0; o >>= 1) m = fmaxf(m, __shfl_down(m, o, 64));
  __syncthreads();
  if ((tid & 63) == 0) red[tid >> 6] = m;
  __syncthreads();
  float M = fmaxf(fmaxf(red[0], red[1]), fmaxf(red[2], red[3]));
  float e0 = __expf(a0 - M), e1 = __expf(a1 - M);
  float s = e0 + e1;
#pragma unroll
  for (int o = 32; o > 0; o >>= 1) s += __shfl_down(s, o, 64);
  __syncthreads();
  if ((tid & 63) == 0) red[tid >> 6] = s;
  __syncthreads();
  float S = red[0] + red[1] + red[2] + red[3];
  float scale = (1.f - p) / S;
  copy_dist[(size_t)r * LL + tid] = e0 * scale;
  copy_dist[(size_t)r * LL + 256 + tid] = e1 * scale;
}

// ---------- kernel 4: bf16 MFMA GEMM ----------
// Round-4: identical sync STRUCTURE to round-3 (passed; 3-buffer, counted
// vmcnt(4), raw s_barrier, T2 swizzle, x3 unroll) but with the fence set cut
// to the correctness-minimum: ONE sched_barrier(0) AFTER s_barrier (stops
// ds_reads hoisting above the barrier -- the round-1 race). The fences after
// STAGE / before barrier were m141-style order-pinning (VALUBusy 57->16%,
// +17us) and are removed; the asm "memory" clobber on vmcnt still orders the
// memory intrinsics across iterations, preserving the vmcnt count.
__global__ __launch_bounds__(256) void k_gemm_mfma(
    const __bf16* __restrict__ Xb, const __bf16* __restrict__ Wtb,
    const float* __restrict__ bias, float* __restrict__ out,
    float* __restrict__ rsum) {
  __shared__ __align__(16) __bf16 As[3][128 * 32];  // [m][k-chunk swizzled]
  __shared__ __align__(16) __bf16 Bs[3][128 * 32];  // [n][k-chunk swizzled]
  int tid = threadIdx.x;
  int lane = tid & 63, wave = tid >> 6;
  int wr = wave >> 1, wc = wave & 1;
  int l15 = lane & 15, quad = lane >> 4;

  // bijective XCD remap (m204 form), m-fastest
  int lid = blockIdx.x;
  int xcd = lid & 7, sub = lid >> 3;
  const int q = NWG >> 3, rr = NWG & 7;   // 218, 6
  int wg = (xcd < rr) ? (xcd * (q + 1) + sub)
                      : (rr * (q + 1) + (xcd - rr) * q + sub);
  int m0 = (wg % NMT) * 128;
  int n0 = (wg / NMT) * 128;

  f32x4 acc[4][4];
#pragma unroll
  for (int mi = 0; mi < 4; ++mi)
#pragma unroll
    for (int ni = 0; ni < 4; ++ni) acc[mi][ni] = (f32x4){0.f, 0.f, 0.f, 0.f};

  int r0 = wave * 32;
  int lr = lane >> 2;                         // 0..15: row within 16-row group
  int chunk = (lane & 3) ^ ((lr >> 1) & 3);   // inverse-swizzled source chunk
  const __bf16* aptr0 = Xb + (size_t)(m0 + r0 + lr) * HH + chunk * 8;
  const __bf16* aptr1 = aptr0 + (size_t)16 * HH;        // (row+16)>>1 &3 same
  const size_t bstep = (size_t)VV * 32;
  const __bf16* bptr0 = Wtb + (size_t)(n0 + r0 + lr) * 32 + chunk * 8;
  const __bf16* bptr1 = bptr0 + (size_t)16 * 32;

  int sw8 = (quad ^ ((l15 >> 1) & 3)) * 8;    // swizzled read slot (bf16 elems)

#define STAGE(it, buf) do {                                          \
    gload16(aptr0 + (size_t)(it) * 32, &As[buf][r0 * 32]);           \
    gload16(aptr1 + (size_t)(it) * 32, &As[buf][(r0 + 16) * 32]);    \
    gload16(bptr0 + (size_t)(it) * bstep, &Bs[buf][r0 * 32]);        \
    gload16(bptr1 + (size_t)(it) * bstep, &Bs[buf][(r0 + 16) * 32]); \
  } while (0)

#define SYNCW(n) do {                                          \
    asm volatile("s_waitcnt vmcnt(" #n ")" ::: "memory");      \
    __builtin_amdgcn_s_barrier();                              \
    __builtin_amdgcn_sched_barrier(0);                         \
  } while (0)

#define COMPUTE(buf) do {                                                     \
    const __bf16* Ab = As[buf];                                               \
    const __bf16* Bb = Bs[buf];                                               \
    bf16x8 af[4], bfg[4];                                                     \
    _Pragma("unroll")                                                         \
    for (int mi = 0; mi < 4; ++mi)                                            \
      af[mi] = *(const bf16x8*)&Ab[(wr * 64 + mi * 16 + l15) * 32 + sw8];     \
    _Pragma("unroll")                                                         \
    for (int ni = 0; ni < 4; ++ni)                                            \
      bfg[ni] = *(const bf16x8*)&Bb[(wc * 64 + ni * 16 + l15) * 32 + sw8];    \
    _Pragma("unroll")                                                         \
    for (int mi = 0; mi < 4; ++mi)                                            \
      _Pragma("unroll")                                                       \
      for (int ni = 0; ni < 4; ++ni)                                          \
        acc[mi][ni] = __builtin_amdgcn_mfma_f32_16x16x32_bf16(                \
            af[mi], bfg[ni], acc[mi][ni], 0, 0, 0);                           \
  } while (0)

  // prologue: 2 tiles in flight
  STAGE(0, 0);
  STAGE(1, 1);
  // steady state: vmcnt(4) = own outstanding stage(it)+stage(it+1)=8 loads,
  // wait retires stage(it); barrier publishes all waves' shares.
  for (int itb = 0; itb < 30; itb += 3) {
    SYNCW(4); STAGE(itb + 2, 2); COMPUTE(0);
    SYNCW(4); STAGE(itb + 3, 0); COMPUTE(1);
    SYNCW(4); STAGE(itb + 4, 1); COMPUTE(2);
  }
  SYNCW(4);   // stage(30) done (stage(31) still in flight)
  COMPUTE(0);
  SYNCW(0);   // drain stage(31)
  COMPUTE(1);

  // bias loaded here so vmcnt in the loop counted only stage loads
  float bv4[4];
#pragma unroll
  for (int ni = 0; ni < 4; ++ni) bv4[ni] = bias[n0 + wc * 64 + ni * 16 + l15];

#pragma unroll
  for (int mi = 0; mi < 4; ++mi) {
#pragma unroll
    for (int rg = 0; rg < 4; ++rg) {
      int row = m0 + wr * 64 + mi * 16 + quad * 4 + rg;
      bool valid = row < NROWS;
      float esum = 0.f;
#pragma unroll
      for (int ni = 0; ni < 4; ++ni) {
        int col = n0 + wc * 64 + ni * 16 + l15;
        float v = acc[mi][ni][rg] + bv4[ni];
        if (valid) out[(size_t)row * VV + col] = v;
        esum += __expf(v);
      }
#pragma unroll
      for (int o = 8; o > 0; o >>= 1) esum += __shfl_down(esum, o, 16);
      if (l15 == 0 && valid) atomicAdd(&rsum[row], esum);
    }
  }
#undef STAGE
#undef SYNCW
#undef COMPUTE
}

// ---------- kernel 5: fused affine log-shift + scatter fix-up (per row) -----
// Hash build (LDS atomics) overlaps the streaming 128 KB affine pass.
// __syncthreads() orders: (a) hash complete, (b) this block's affine global
// writes visible to this block (same CU/L1) before the fix-up read-modify.
__global__ __launch_bounds__(256) void k_affine_scatter(
    float* __restrict__ out, const float* __restrict__ p_gen,
    const float* __restrict__ rsum, const int* __restrict__ enc,
    const float* __restrict__ copy) {
  __shared__ int hkey[1024];
  __shared__ float hval[1024];
  int r = blockIdx.x, tid = threadIdx.x;
  float* row = out + (size_t)r * VV;
  float logc = __logf(p_gen[r] / rsum[r]);
  for (int i = tid; i < 1024; i += 256) { hkey[i] = -1; hval[i] = 0.f; }
  __syncthreads();
  int b = r / TT;
  for (int j = tid; j < LL; j += 256) {
    int v = enc[(size_t)b * LL + j];
    float cv = copy[(size_t)r * LL + j];
    unsigned h = ((unsigned)v * 2654435761u) & 1023u;
    while (true) {
      int prev = atomicCAS(&hkey[h], -1, v);
      if (prev == -1 || prev == v) { atomicAdd(&hval[h], cv); break; }
      h = (h + 1) & 1023u;
    }
  }
  for (int c4 = tid; c4 < VV / 4; c4 += 256) {
    float4 v = ((float4*)row)[c4];
    v.x += logc; v.y += logc; v.z += logc; v.w += logc;
    ((float4*)row)[c4] = v;
  }
  __syncthreads();
  for (int h = tid; h < 1024; h += 256) {
    int col = hkey[h];
    if (col >= 0) {
      float stored = row[col];  // = log(p_gen*softmax) at this col
      row[col] = __logf(__expf(stored) + hval[h]);
    }
  }
}

extern "C" void kernel_launch(void* const* d_in, const int* in_sizes, int n_in,
                              void* d_out, int out_size, void* d_ws, size_t ws_size,
                              hipStream_t stream) {
  const float* x    = (const float*)d_in[0];
  const float* attn = (const float*)d_in[1];
  const int*   enc  = (const int*)d_in[2];
  const float* Wv   = (const float*)d_in[3];
  const float* bv   = (const float*)d_in[4];
  const float* wgen = (const float*)d_in[5];
  const float* bg   = (const float*)d_in[6];
  float* out = (float*)d_out;
  float* ws = (float*)d_ws;

  float* p_gen = ws;                                   // 1024 floats
  float* rsum  = ws + 1024;                            // 1024 floats
  float* copy  = ws + 2048;                            // 800*512 floats
  __bf16* xb = (__bf16*)(ws + 2048 + NROWS * LL);      // 896*1024 bf16
  __bf16* Wt = (__bf16*)((char*)xb + (size_t)MPAD * HH * 2);  // 32000*1024 bf16 (blocked)

  k_cvt_x<<<MPAD * HH / 4 / 256, 256, 0, stream>>>(x, xb);
  dim3 gw(VV / 256, HH / 32);   // (125, 32)
  k_cvt_wT<<<gw, 256, 0, stream>>>(Wv, Wt);
  k_pgen_copy<<<NROWS, 256, 0, stream>>>(x, attn, wgen, bg, p_gen, copy, rsum);
  k_gemm_mfma<<<NWG, 256, 0, stream>>>(xb, Wt, bv, out, rsum);
  k_affine_scatter<<<NROWS, 256, 0, stream>>>(out, p_gen, rsum, enc, copy);
}

// Round 5
// 386.936 us; speedup vs baseline: 1.0490x; 1.0490x over previous
//
#include <hip/hip_runtime.h>
#include <math.h>

#define BB 8
#define TT 100
#define HH 1024
#define LL 512
#define VV 32000
#define NROWS (BB*TT)   // 800
#define MPAD 896        // 7 tiles of 128
#define NMT 7           // m tiles
#define NNT 250         // n tiles
#define NWG (NMT*NNT)   // 1750

typedef __bf16 bf16x8 __attribute__((ext_vector_type(8)));
typedef __bf16 bf16x4 __attribute__((ext_vector_type(4)));
typedef float f32x4 __attribute__((ext_vector_type(4)));

__device__ __forceinline__ void gload16(const void* g, void* l) {
  __builtin_amdgcn_global_load_lds(
      (const __attribute__((address_space(1))) unsigned int*)g,
      (__attribute__((address_space(3))) unsigned int*)l, 16, 0, 0);
}

// ---------- kernel 1: x fp32 -> bf16, zero-padded to 896 rows ----------
__global__ __launch_bounds__(256) void k_cvt_x(const float* __restrict__ x,
                                               __bf16* __restrict__ xb) {
  int idx = blockIdx.x * 256 + threadIdx.x;   // one float4 per thread
  int row = (idx * 4) >> 10;
  bf16x4 v;
  if (row < NROWS) {
    float4 f = ((const float4*)x)[idx];
    v[0] = (__bf16)f.x; v[1] = (__bf16)f.y; v[2] = (__bf16)f.z; v[3] = (__bf16)f.w;
  } else {
    v[0] = v[1] = v[2] = v[3] = (__bf16)0.f;
  }
  ((bf16x4*)xb)[idx] = v;
}

// ---------- kernel 2: p_gen + copy distribution (+ rsum zero-init) ----------
__global__ __launch_bounds__(256) void k_pgen_copy(
    const float* __restrict__ x, const float* __restrict__ attn,
    const float* __restrict__ w_gen, const float* __restrict__ b_gen,
    float* __restrict__ p_gen, float* __restrict__ copy_dist,
    float* __restrict__ rsum) {
  int r = blockIdx.x;
  int tid = threadIdx.x;
  __shared__ float red[4];
  if (tid == 0) rsum[r] = 0.f;

  float d = 0.f;
  for (int h = tid; h < HH; h += 256) d += x[(size_t)r * HH + h] * w_gen[h];
#pragma unroll
  for (int o = 32; o > 0; o >>= 1) d += __shfl_down(d, o, 64);
  if ((tid & 63) == 0) red[tid >> 6] = d;
  __syncthreads();
  float dot = red[0] + red[1] + red[2] + red[3];
  float p = 1.f / (1.f + __expf(-(dot + b_gen[0])));
  if (tid == 0) p_gen[r] = p;

  float a0 = attn[(size_t)r * LL + tid];
  float a1 = attn[(size_t)r * LL + 256 + tid];
  float m = fmaxf(a0, a1);
#pragma unroll
  for (int o = 32; o > 0; o >>= 1) m = fmaxf(m, __shfl_down(m, o, 64));
  __syncthreads();
  if ((tid & 63) == 0) red[tid >> 6] = m;
  __syncthreads();
  float M = fmaxf(fmaxf(red[0], red[1]), fmaxf(red[2], red[3]));
  float e0 = __expf(a0 - M), e1 = __expf(a1 - M);
  float s = e0 + e1;
#pragma unroll
  for (int o = 32; o > 0; o >>= 1) s += __shfl_down(s, o, 64);
  __syncthreads();
  if ((tid & 63) == 0) red[tid >> 6] = s;
  __syncthreads();
  float S = red[0] + red[1] + red[2] + red[3];
  float scale = (1.f - p) / S;
  copy_dist[(size_t)r * LL + tid] = e0 * scale;
  copy_dist[(size_t)r * LL + 256 + tid] = e1 * scale;
}

// ---------- kernel 3: bf16 MFMA GEMM, W converted in-kernel ----------
// Round-5: REVERT to the proven round-2 sync structure (2-buffer,
// __syncthreads full drain per iter -- 97us known-good), plus:
//  * k_cvt_wT DELETED: B staged from W fp32 directly. Per iter, each thread
//    loads a 4x4 fp32 block of W (4x float4, coalesced 512B/wave-row) BEFORE
//    COMPUTE, converts + transposes in-reg and ds_writes AFTER COMPUTE
//    (T14 issue-early/write-late: HBM latency hides under the MFMA block).
//    The __syncthreads drain now only waits A's 2 gload_lds (L2-resident).
//  * T2 swizzle kept: LDS slot s of row n holds k-chunk s ^ ((n>>1)&3);
//    read path is byte-identical to the passing round-3/4 kernels.
__global__ __launch_bounds__(256) void k_gemm_mfma(
    const __bf16* __restrict__ Xb, const float* __restrict__ Wv,
    const float* __restrict__ bias, float* __restrict__ out,
    float* __restrict__ rsum) {
  __shared__ __align__(16) __bf16 As[2][128 * 32];  // [m][k-chunk swizzled]
  __shared__ __align__(16) __bf16 Bs[2][128 * 32];  // [n][k-chunk swizzled]
  int tid = threadIdx.x;
  int lane = tid & 63, wave = tid >> 6;
  int wr = wave >> 1, wc = wave & 1;
  int l15 = lane & 15, quad = lane >> 4;

  // bijective XCD remap (m204 form), m-fastest: 7 sharers of a W n-panel
  // are consecutive wgs on one XCD.
  int lid = blockIdx.x;
  int xcd = lid & 7, sub = lid >> 3;
  const int q = NWG >> 3, rr = NWG & 7;   // 218, 6
  int wg = (xcd < rr) ? (xcd * (q + 1) + sub)
                      : (rr * (q + 1) + (xcd - rr) * q + sub);
  int m0 = (wg % NMT) * 128;
  int n0 = (wg / NMT) * 128;

  f32x4 acc[4][4];
#pragma unroll
  for (int mi = 0; mi < 4; ++mi)
#pragma unroll
    for (int ni = 0; ni < 4; ++ni) acc[mi][ni] = (f32x4){0.f, 0.f, 0.f, 0.f};

  // ---- A staging (unchanged, proven): gload_lds from pre-swizzled source
  int r0 = wave * 32;
  int lr = lane >> 2;                         // row within 16-row group
  int chunk = (lane & 3) ^ ((lr >> 1) & 3);   // inverse-swizzled source chunk
  const __bf16* aptr0 = Xb + (size_t)(m0 + r0 + lr) * HH + chunk * 8;
  const __bf16* aptr1 = aptr0 + (size_t)16 * HH;
  __bf16* lA0[2] = {&As[0][r0 * 32], &As[1][r0 * 32]};
  __bf16* lA1[2] = {&As[0][(r0 + 16) * 32], &As[1][(r0 + 16) * 32]};

  // ---- B staging (new): thread t owns n-rows nq*4..+3, k-cols kb*4..+3
  int nq = tid & 31;    // n-quad
  int kb = tid >> 5;    // 0..7 k-subblock
  const int rn0 = nq * 4;
  const int bslot = (kb >> 1);       // k-chunk this thread's data belongs to
  const int bsub = (kb & 1) * 4;     // elem offset within 16B slot
  // float4 source base: row k = kb*4, col n0 + nq*4
  const float4* wsrc = (const float4*)Wv + (size_t)(kb * 4) * (VV / 4) + (n0 + nq * 4) / 4;

  int sw8 = (quad ^ ((l15 >> 1) & 3)) * 8;    // swizzled read slot

#define STAGEA(it, buf) do {                        \
    gload16(aptr0 + (size_t)(it) * 32, lA0[buf]);   \
    gload16(aptr1 + (size_t)(it) * 32, lA1[buf]);   \
  } while (0)

#define LOADB(it) do {                                          \
    _Pragma("unroll")                                           \
    for (int jj = 0; jj < 4; ++jj)                              \
      wv[jj] = wsrc[(size_t)((it) * 32 + jj) * (VV / 4)];       \
  } while (0)

#define WRITEB(buf) do {                                              \
    _Pragma("unroll")                                                 \
    for (int i = 0; i < 4; ++i) {                                     \
      int rn = rn0 + i;                                               \
      bf16x4 bv;                                                      \
      bv[0] = (__bf16)wv[0][i]; bv[1] = (__bf16)wv[1][i];             \
      bv[2] = (__bf16)wv[2][i]; bv[3] = (__bf16)wv[3][i];             \
      int slot = bslot ^ ((rn >> 1) & 3);                             \
      *(bf16x4*)&Bs[buf][rn * 32 + slot * 8 + bsub] = bv;             \
    }                                                                 \
  } while (0)

#define COMPUTE(buf) do {                                                     \
    const __bf16* Ab = As[buf];                                               \
    const __bf16* Bb = Bs[buf];                                               \
    bf16x8 af[4], bfg[4];                                                     \
    _Pragma("unroll")                                                         \
    for (int mi = 0; mi < 4; ++mi)                                            \
      af[mi] = *(const bf16x8*)&Ab[(wr * 64 + mi * 16 + l15) * 32 + sw8];     \
    _Pragma("unroll")                                                         \
    for (int ni = 0; ni < 4; ++ni)                                            \
      bfg[ni] = *(const bf16x8*)&Bb[(wc * 64 + ni * 16 + l15) * 32 + sw8];    \
    _Pragma("unroll")                                                         \
    for (int mi = 0; mi < 4; ++mi)                                            \
      _Pragma("unroll")                                                       \
      for (int ni = 0; ni < 4; ++ni)                                          \
        acc[mi][ni] = __builtin_amdgcn_mfma_f32_16x16x32_bf16(                \
            af[mi], bfg[ni], acc[mi][ni], 0, 0, 0);                           \
  } while (0)

  float4 wv[4];
  // prologue: stage k-slice 0 into buffer 0
  STAGEA(0, 0);
  LOADB(0);
  WRITEB(0);

  for (int it = 0; it < 32; ++it) {
    int cur = it & 1;
    __syncthreads();   // drains A gloads (vmcnt) + all waves' B ds_writes (lgkm)
    int nxt = cur ^ 1;
    if (it + 1 < 32) {
      STAGEA(it + 1, nxt);   // async into LDS
      LOADB(it + 1);         // issue global->reg now; consumed after COMPUTE
    }
    COMPUTE(cur);
    if (it + 1 < 32) WRITEB(nxt);   // cvt+ds_write; buf[nxt] reads done pre-barrier
  }

  float bv4[4];
#pragma unroll
  for (int ni = 0; ni < 4; ++ni) bv4[ni] = bias[n0 + wc * 64 + ni * 16 + l15];

#pragma unroll
  for (int mi = 0; mi < 4; ++mi) {
#pragma unroll
    for (int rg = 0; rg < 4; ++rg) {
      int row = m0 + wr * 64 + mi * 16 + quad * 4 + rg;
      bool valid = row < NROWS;
      float esum = 0.f;
#pragma unroll
      for (int ni = 0; ni < 4; ++ni) {
        int col = n0 + wc * 64 + ni * 16 + l15;
        float v = acc[mi][ni][rg] + bv4[ni];
        if (valid) out[(size_t)row * VV + col] = v;
        esum += __expf(v);
      }
#pragma unroll
      for (int o = 8; o > 0; o >>= 1) esum += __shfl_down(esum, o, 16);
      if (l15 == 0 && valid) atomicAdd(&rsum[row], esum);
    }
  }
#undef STAGEA
#undef LOADB
#undef WRITEB
#undef COMPUTE
}

// ---------- kernel 4: fused affine log-shift + scatter fix-up (per row) -----
__global__ __launch_bounds__(256) void k_affine_scatter(
    float* __restrict__ out, const float* __restrict__ p_gen,
    const float* __restrict__ rsum, const int* __restrict__ enc,
    const float* __restrict__ copy) {
  __shared__ int hkey[1024];
  __shared__ float hval[1024];
  int r = blockIdx.x, tid = threadIdx.x;
  float* row = out + (size_t)r * VV;
  float logc = __logf(p_gen[r] / rsum[r]);
  for (int i = tid; i < 1024; i += 256) { hkey[i] = -1; hval[i] = 0.f; }
  __syncthreads();
  int b = r / TT;
  for (int j = tid; j < LL; j += 256) {
    int v = enc[(size_t)b * LL + j];
    float cv = copy[(size_t)r * LL + j];
    unsigned h = ((unsigned)v * 2654435761u) & 1023u;
    while (true) {
      int prev = atomicCAS(&hkey[h], -1, v);
      if (prev == -1 || prev == v) { atomicAdd(&hval[h], cv); break; }
      h = (h + 1) & 1023u;
    }
  }
  for (int c4 = tid; c4 < VV / 4; c4 += 256) {
    float4 v = ((float4*)row)[c4];
    v.x += logc; v.y += logc; v.z += logc; v.w += logc;
    ((float4*)row)[c4] = v;
  }
  __syncthreads();
  for (int h = tid; h < 1024; h += 256) {
    int col = hkey[h];
    if (col >= 0) {
      float stored = row[col];  // = log(p_gen*softmax) at this col
      row[col] = __logf(__expf(stored) + hval[h]);
    }
  }
}

extern "C" void kernel_launch(void* const* d_in, const int* in_sizes, int n_in,
                              void* d_out, int out_size, void* d_ws, size_t ws_size,
                              hipStream_t stream) {
  const float* x    = (const float*)d_in[0];
  const float* attn = (const float*)d_in[1];
  const int*   enc  = (const int*)d_in[2];
  const float* Wv   = (const float*)d_in[3];
  const float* bv   = (const float*)d_in[4];
  const float* wgen = (const float*)d_in[5];
  const float* bg   = (const float*)d_in[6];
  float* out = (float*)d_out;
  float* ws = (float*)d_ws;

  float* p_gen = ws;                                   // 1024 floats
  float* rsum  = ws + 1024;                            // 1024 floats
  float* copy  = ws + 2048;                            // 800*512 floats
  __bf16* xb = (__bf16*)(ws + 2048 + NROWS * LL);      // 896*1024 bf16

  k_cvt_x<<<MPAD * HH / 4 / 256, 256, 0, stream>>>(x, xb);
  k_pgen_copy<<<NROWS, 256, 0, stream>>>(x, attn, wgen, bg, p_gen, copy, rsum);
  k_gemm_mfma<<<NWG, 256, 0, stream>>>(xb, Wv, bv, out, rsum);
  k_affine_scatter<<<NROWS, 256, 0, stream>>>(out, p_gen, rsum, enc, copy);
}

// Round 6
// 371.877 us; speedup vs baseline: 1.0915x; 1.0405x over previous
//
#include <hip/hip_runtime.h>
#include <math.h>

#define BB 8
#define TT 100
#define HH 1024
#define LL 512
#define VV 32000
#define NROWS (BB*TT)   // 800
#define MPAD 896        // 7 tiles of 128
#define NMT 7           // m tiles
#define NNT 250         // n tiles
#define NWG (NMT*NNT)   // 1750

typedef __bf16 bf16x8 __attribute__((ext_vector_type(8)));
typedef __bf16 bf16x4 __attribute__((ext_vector_type(4)));
typedef float f32x4 __attribute__((ext_vector_type(4)));

__device__ __forceinline__ void gload16(const void* g, void* l) {
  __builtin_amdgcn_global_load_lds(
      (const __attribute__((address_space(1))) unsigned int*)g,
      (__attribute__((address_space(3))) unsigned int*)l, 16, 0, 0);
}

// ---------- kernel 1: fused x->bf16 conversion + p_gen + copy dist ----------
// Blocks 0..799: convert row, p_gen dot (float4-vectorized), copy softmax.
// Blocks 800..895: zero-pad xb rows only.
__global__ __launch_bounds__(256) void k_pgen_copy(
    const float* __restrict__ x, const float* __restrict__ attn,
    const float* __restrict__ w_gen, const float* __restrict__ b_gen,
    float* __restrict__ p_gen, float* __restrict__ copy_dist,
    float* __restrict__ rsum, __bf16* __restrict__ xb) {
  int r = blockIdx.x;
  int tid = threadIdx.x;
  if (r >= NROWS) {
    bf16x4 z; z[0] = z[1] = z[2] = z[3] = (__bf16)0.f;
    ((bf16x4*)(xb + (size_t)r * HH))[tid] = z;
    return;
  }
  __shared__ float red[4];
  if (tid == 0) rsum[r] = 0.f;

  float4 f = ((const float4*)(x + (size_t)r * HH))[tid];
  bf16x4 v;
  v[0] = (__bf16)f.x; v[1] = (__bf16)f.y; v[2] = (__bf16)f.z; v[3] = (__bf16)f.w;
  ((bf16x4*)(xb + (size_t)r * HH))[tid] = v;

  float4 w = ((const float4*)w_gen)[tid];
  float d = f.x * w.x + f.y * w.y + f.z * w.z + f.w * w.w;
#pragma unroll
  for (int o = 32; o > 0; o >>= 1) d += __shfl_down(d, o, 64);
  if ((tid & 63) == 0) red[tid >> 6] = d;
  __syncthreads();
  float dot = red[0] + red[1] + red[2] + red[3];
  float p = 1.f / (1.f + __expf(-(dot + b_gen[0])));
  if (tid == 0) p_gen[r] = p;

  float a0 = attn[(size_t)r * LL + tid];
  float a1 = attn[(size_t)r * LL + 256 + tid];
  float m = fmaxf(a0, a1);
#pragma unroll
  for (int o = 32; o > 0; o >>= 1) m = fmaxf(m, __shfl_down(m, o, 64));
  __syncthreads();
  if ((tid & 63) == 0) red[tid >> 6] = m;
  __syncthreads();
  float M = fmaxf(fmaxf(red[0], red[1]), fmaxf(red[2], red[3]));
  float e0 = __expf(a0 - M), e1 = __expf(a1 - M);
  float s = e0 + e1;
#pragma unroll
  for (int o = 32; o > 0; o >>= 1) s += __shfl_down(s, o, 64);
  __syncthreads();
  if ((tid & 63) == 0) red[tid >> 6] = s;
  __syncthreads();
  float S = red[0] + red[1] + red[2] + red[3];
  float scale = (1.f - p) / S;
  copy_dist[(size_t)r * LL + tid] = e0 * scale;
  copy_dist[(size_t)r * LL + 256 + tid] = e1 * scale;
}

// ---------- kernel 2: bf16 MFMA GEMM, W fp32 converted in-kernel ----------
// Round-6 fixes vs round-5 (same drain-barrier structure, proven sync):
//  (1) B slot swizzle (rn>>2)&3 (= nq&3, thread-constant on write). Round-5's
//      (rn>>1)&3 left write banks degenerate (rn stride 4 -> 256B -> bank
//      stride 0; slot varied only with l&1) = 32-way conflict, 2.5e7 counted.
//      Now 4-slot spread across lanes -> 16 banks/instr = 2x ideal only.
//      Read side: slot = quad ^ ((l15>>2)&3) -> 2-way (free). A path and its
//      (row>>1)&3 swizzle byte-identical to the passing r3/r4 kernels.
//  (2) LOADB issued BEFORE STAGEA: vmcnt retires in issue order, so WRITEB
//      waits only vmcnt(2) (B's 4 loads) and A's gload_lds stay in flight
//      until the barrier -- hidden under COMPUTE.
__global__ __launch_bounds__(256) void k_gemm_mfma(
    const __bf16* __restrict__ Xb, const float* __restrict__ Wv,
    const float* __restrict__ bias, float* __restrict__ out,
    float* __restrict__ rsum) {
  __shared__ __align__(16) __bf16 As[2][128 * 32];
  __shared__ __align__(16) __bf16 Bs[2][128 * 32];
  int tid = threadIdx.x;
  int lane = tid & 63, wave = tid >> 6;
  int wr = wave >> 1, wc = wave & 1;
  int l15 = lane & 15, quad = lane >> 4;

  // bijective XCD remap (m204 form), m-fastest
  int lid = blockIdx.x;
  int xcd = lid & 7, sub = lid >> 3;
  const int q = NWG >> 3, rr = NWG & 7;   // 218, 6
  int wg = (xcd < rr) ? (xcd * (q + 1) + sub)
                      : (rr * (q + 1) + (xcd - rr) * q + sub);
  int m0 = (wg % NMT) * 128;
  int n0 = (wg / NMT) * 128;

  f32x4 acc[4][4];
#pragma unroll
  for (int mi = 0; mi < 4; ++mi)
#pragma unroll
    for (int ni = 0; ni < 4; ++ni) acc[mi][ni] = (f32x4){0.f, 0.f, 0.f, 0.f};

  // ---- A staging (proven): gload_lds, pre-swizzled source, g_A=(row>>1)&3
  int r0 = wave * 32;
  int lr = lane >> 2;
  int chunk = (lane & 3) ^ ((lr >> 1) & 3);
  const __bf16* aptr0 = Xb + (size_t)(m0 + r0 + lr) * HH + chunk * 8;
  const __bf16* aptr1 = aptr0 + (size_t)16 * HH;
  __bf16* lA0[2] = {&As[0][r0 * 32], &As[1][r0 * 32]};
  __bf16* lA1[2] = {&As[0][(r0 + 16) * 32], &As[1][(r0 + 16) * 32]};

  // ---- B staging: thread owns n-rows nq*4..+3, k-rows kb*4..+3
  int nq = tid & 31;
  int kb = tid >> 5;                 // 0..7
  const int rn0 = nq * 4;
  const int bslot = kb >> 1;         // k-chunk
  const int bsub = (kb & 1) * 4;     // elem offset within chunk
  const int wslot = bslot ^ (nq & 3);   // swizzled write slot (g_B=(rn>>2)&3)
  const float4* wsrc = (const float4*)Wv + (size_t)(kb * 4) * (VV / 4) + (n0 + nq * 4) / 4;

  int swA8 = (quad ^ ((l15 >> 1) & 3)) * 8;   // A read slot
  int swB8 = (quad ^ ((l15 >> 2) & 3)) * 8;   // B read slot

#define STAGEA(it, buf) do {                        \
    gload16(aptr0 + (size_t)(it) * 32, lA0[buf]);   \
    gload16(aptr1 + (size_t)(it) * 32, lA1[buf]);   \
  } while (0)

#define LOADB(it) do {                                          \
    _Pragma("unroll")                                           \
    for (int jj = 0; jj < 4; ++jj)                              \
      wv[jj] = wsrc[(size_t)((it) * 32 + jj) * (VV / 4)];       \
  } while (0)

#define WRITEB(buf) do {                                              \
    _Pragma("unroll")                                                 \
    for (int i = 0; i < 4; ++i) {                                     \
      int rn = rn0 + i;                                               \
      bf16x4 bv;                                                      \
      bv[0] = (__bf16)wv[0][i]; bv[1] = (__bf16)wv[1][i];             \
      bv[2] = (__bf16)wv[2][i]; bv[3] = (__bf16)wv[3][i];             \
      *(bf16x4*)&Bs[buf][rn * 32 + wslot * 8 + bsub] = bv;            \
    }                                                                 \
  } while (0)

#define COMPUTE(buf) do {                                                     \
    const __bf16* Ab = As[buf];                                               \
    const __bf16* Bb = Bs[buf];                                               \
    bf16x8 af[4], bfg[4];                                                     \
    _Pragma("unroll")                                                         \
    for (int mi = 0; mi < 4; ++mi)                                            \
      af[mi] = *(const bf16x8*)&Ab[(wr * 64 + mi * 16 + l15) * 32 + swA8];    \
    _Pragma("unroll")                                                         \
    for (int ni = 0; ni < 4; ++ni)                                            \
      bfg[ni] = *(const bf16x8*)&Bb[(wc * 64 + ni * 16 + l15) * 32 + swB8];   \
    _Pragma("unroll")                                                         \
    for (int mi = 0; mi < 4; ++mi)                                            \
      _Pragma("unroll")                                                       \
      for (int ni = 0; ni < 4; ++ni)                                          \
        acc[mi][ni] = __builtin_amdgcn_mfma_f32_16x16x32_bf16(                \
            af[mi], bfg[ni], acc[mi][ni], 0, 0, 0);                           \
  } while (0)

  float4 wv[4];
  // prologue: stage k-slice 0 into buffer 0
  LOADB(0);
  STAGEA(0, 0);
  WRITEB(0);

  for (int it = 0; it < 32; ++it) {
    int cur = it & 1;
    __syncthreads();   // drains A gloads (vmcnt) + all waves' B ds_writes (lgkm)
    int nxt = cur ^ 1;
    if (it + 1 < 32) {
      LOADB(it + 1);         // B global->reg first (retires at vmcnt(2))
      STAGEA(it + 1, nxt);   // A async into LDS, in flight until barrier
    }
    COMPUTE(cur);
    if (it + 1 < 32) WRITEB(nxt);   // cvt+ds_write; needs only B loads done
  }

  float bv4[4];
#pragma unroll
  for (int ni = 0; ni < 4; ++ni) bv4[ni] = bias[n0 + wc * 64 + ni * 16 + l15];

#pragma unroll
  for (int mi = 0; mi < 4; ++mi) {
#pragma unroll
    for (int rg = 0; rg < 4; ++rg) {
      int row = m0 + wr * 64 + mi * 16 + quad * 4 + rg;
      bool valid = row < NROWS;
      float esum = 0.f;
#pragma unroll
      for (int ni = 0; ni < 4; ++ni) {
        int col = n0 + wc * 64 + ni * 16 + l15;
        float v = acc[mi][ni][rg] + bv4[ni];
        if (valid) out[(size_t)row * VV + col] = v;
        esum += __expf(v);
      }
#pragma unroll
      for (int o = 8; o > 0; o >>= 1) esum += __shfl_down(esum, o, 16);
      if (l15 == 0 && valid) atomicAdd(&rsum[row], esum);
    }
  }
#undef STAGEA
#undef LOADB
#undef WRITEB
#undef COMPUTE
}

// ---------- kernel 3: fused affine log-shift + scatter fix-up (per row) -----
__global__ __launch_bounds__(256) void k_affine_scatter(
    float* __restrict__ out, const float* __restrict__ p_gen,
    const float* __restrict__ rsum, const int* __restrict__ enc,
    const float* __restrict__ copy) {
  __shared__ int hkey[1024];
  __shared__ float hval[1024];
  int r = blockIdx.x, tid = threadIdx.x;
  float* row = out + (size_t)r * VV;
  float logc = __logf(p_gen[r] / rsum[r]);
  for (int i = tid; i < 1024; i += 256) { hkey[i] = -1; hval[i] = 0.f; }
  __syncthreads();
  int b = r / TT;
  for (int j = tid; j < LL; j += 256) {
    int v = enc[(size_t)b * LL + j];
    float cv = copy[(size_t)r * LL + j];
    unsigned h = ((unsigned)v * 2654435761u) & 1023u;
    while (true) {
      int prev = atomicCAS(&hkey[h], -1, v);
      if (prev == -1 || prev == v) { atomicAdd(&hval[h], cv); break; }
      h = (h + 1) & 1023u;
    }
  }
  for (int c4 = tid; c4 < VV / 4; c4 += 256) {
    float4 v = ((float4*)row)[c4];
    v.x += logc; v.y += logc; v.z += logc; v.w += logc;
    ((float4*)row)[c4] = v;
  }
  __syncthreads();
  for (int h = tid; h < 1024; h += 256) {
    int col = hkey[h];
    if (col >= 0) {
      float stored = row[col];  // = log(p_gen*softmax) at this col
      row[col] = __logf(__expf(stored) + hval[h]);
    }
  }
}

extern "C" void kernel_launch(void* const* d_in, const int* in_sizes, int n_in,
                              void* d_out, int out_size, void* d_ws, size_t ws_size,
                              hipStream_t stream) {
  const float* x    = (const float*)d_in[0];
  const float* attn = (const float*)d_in[1];
  const int*   enc  = (const int*)d_in[2];
  const float* Wv   = (const float*)d_in[3];
  const float* bv   = (const float*)d_in[4];
  const float* wgen = (const float*)d_in[5];
  const float* bg   = (const float*)d_in[6];
  float* out = (float*)d_out;
  float* ws = (float*)d_ws;

  float* p_gen = ws;                                   // 1024 floats
  float* rsum  = ws + 1024;                            // 1024 floats
  float* copy  = ws + 2048;                            // 800*512 floats
  __bf16* xb = (__bf16*)(ws + 2048 + NROWS * LL);      // 896*1024 bf16

  k_pgen_copy<<<MPAD, 256, 0, stream>>>(x, attn, wgen, bg, p_gen, copy, rsum, xb);
  k_gemm_mfma<<<NWG, 256, 0, stream>>>(xb, Wv, bv, out, rsum);
  k_affine_scatter<<<NROWS, 256, 0, stream>>>(out, p_gen, rsum, enc, copy);
}